// Round 12
// baseline (684.290 us; speedup 1.0000x reference)
//
#include <hip/hip_runtime.h>
#include <cmath>

#define BB 4
#define SS 256
#define ZDIM 128
#define GCH 256
#define NBLKS 8
#define NPIX 65536   // 256*256
#define U1C 128      // GC/2

__device__ __forceinline__ float lrelu(float x){ return x >= 0.f ? x : 0.2f*x; }

// ---- fused prep: pool(0..255) + A transpose(256..511) + Am(512..515) + w ----
__global__ __launch_bounds__(256) void k_pp(const float* __restrict__ img,
        const int* __restrict__ seg, float* __restrict__ segsum,
        float* __restrict__ counts, const float* __restrict__ A,
        const float* __restrict__ w1, const float* __restrict__ w2,
        float* __restrict__ At2, float* __restrict__ Am,
        float* __restrict__ wT, float* __restrict__ w2t){
  int bid = blockIdx.x;
  int tid = threadIdx.x;
  if(bid < 256){
    __shared__ float ls[SS*4];
    for(int j=tid;j<SS*4;j+=256) ls[j]=0.f;
    __syncthreads();
    int b = bid >> 6;
    int base = bid*1024;
    for(int it=0; it<4; it++){
      int idx = base + it*256 + tid;
      int n = idx & (NPIX-1);
      int s = seg[idx];
      atomicAdd(&ls[s*4+0], img[(b*3+0)*NPIX+n]);
      atomicAdd(&ls[s*4+1], img[(b*3+1)*NPIX+n]);
      atomicAdd(&ls[s*4+2], img[(b*3+2)*NPIX+n]);
      atomicAdd(&ls[s*4+3], 1.0f);
    }
    __syncthreads();
    for(int j=tid;j<SS*4;j+=256){
      int s = j>>2, c = j&3;
      float vv = ls[j];
      if(vv != 0.f){
        if(c<3) atomicAdd(&segsum[(b*SS+s)*3+c], vv);
        else    atomicAdd(&counts[b*SS+s], vv);
      }
    }
  } else if(bid < 512){
    __shared__ float t[32][33];
    int sb = bid - 256;
    int b = sb >> 6;
    int bx = (sb & 7)*32, by = ((sb >> 3) & 7)*32;
    int lx = tid & 31, ly4 = (tid >> 5)*4;
    #pragma unroll
    for(int r=0;r<4;r++)
      t[ly4+r][lx] = A[(b<<16) + ((by+ly4+r)<<8) + bx + lx];
    __syncthreads();
    #pragma unroll
    for(int r=0;r<4;r++){
      int jj = bx + ly4 + r;
      int i  = by + lx;
      At2[(b<<16) + ((jj>>2)<<10) + (i<<2) + (jj&3)] = t[lx][ly4+r];
    }
  } else if(bid < 516){
    // Am[b][j] = (1/256) sum_i A[b][i][j]  (deterministic fixed-order sweep)
    int b = bid - 512;
    int j = tid;
    float s0=0.f,s1=0.f,s2=0.f,s3=0.f;
    for(int i=0;i<256;i+=4){
      s0 += A[(b<<16)+((i+0)<<8)+j];
      s1 += A[(b<<16)+((i+1)<<8)+j];
      s2 += A[(b<<16)+((i+2)<<8)+j];
      s3 += A[(b<<16)+((i+3)<<8)+j];
    }
    Am[b*256+j] = ((s0+s1)+(s2+s3))*(1.f/256.f);
  } else {
    int idx = (bid-516)*256 + tid;
    if(idx < 294912){
      int o = idx & 127; int r = idx >> 7; int c = r & 255; int k = r >> 8;
      wT[idx] = w1[(o*GCH + c)*9 + k];
    } else if(idx < 294912 + 3456){
      int t2 = idx - 294912;
      int cc = t2 & 7;
      int oc = (t2 >> 3) % 3;
      int sg = (t2 / 24) & 3;
      int g  = (t2 / 96) & 3;
      int k  = t2 / 384;
      w2t[t2] = w2[oc*1152 + (g*32 + sg*8 + cc)*9 + k];
    }
  }
}

// ---- x0 = WSproj(concat(feats, z)) -> h2a (packed float4 over channels) ----
__global__ __launch_bounds__(256) void k_x0(const float* __restrict__ segsum,
        const float* __restrict__ counts, const float* __restrict__ z,
        const float* __restrict__ pw, const float* __restrict__ pb,
        float sc, float4* __restrict__ xp2){
  int og = blockIdx.x;              // 0..63 (channel group of 4)
  int b  = blockIdx.y;
  int i  = threadIdx.x;             // node
  float cnt = counts[b*SS+i] + 1e-6f;
  float f0 = segsum[(b*SS+i)*3+0]/cnt;
  float f1 = segsum[(b*SS+i)*3+1]/cnt;
  float f2 = segsum[(b*SS+i)*3+2]/cnt;
  const float* zb = z + b*ZDIM;
  float vals[4];
  #pragma unroll
  for(int oo=0;oo<4;oo++){
    int o = og*4 + oo;
    const float* wr = pw + o*131;
    float acc = wr[0]*f0 + wr[1]*f1 + wr[2]*f2;
    #pragma unroll 8
    for(int j=0;j<ZDIM;j++) acc += wr[3+j]*zb[j];
    vals[oo] = acc*sc + pb[o];
  }
  float4 o4 = {vals[0], vals[1], vals[2], vals[3]};
  xp2[(b*64+og)*256 + i] = o4;
}

// ---- one graph iteration in ONE launch: style(bid 0..31) || gemm(32..287) ----
// Both roles read (h2prev, gbPrev) independently; no intra-launch dependency.
__global__ __launch_bounds__(512) void k_iter(
    const float4* __restrict__ h2prev, const float* __restrict__ gbPrev,
    float4* __restrict__ h2next, float* __restrict__ gbNext,
    const float* __restrict__ bw, const float* __restrict__ bb,
    const float* __restrict__ a1w, const float* __restrict__ a1b,
    const float* __restrict__ a2w, const float* __restrict__ a2b,
    const float4* __restrict__ At2, const float* __restrict__ Am,
    float sc, float sc2){
  int bid = blockIdx.x;
  int tid = threadIdx.x;
  int lane = tid & 63, wv = tid >> 6;
  if(bid < 32){
    // ======== style role: q-th 1/8 of gamma/beta rows for batch b ========
    __shared__ float amL[256];
    __shared__ float4 glS4[128];
    __shared__ float4 xm4[64];
    __shared__ float4 mL4[64];
    __shared__ float4 s1L4[128];
    int b = bid & 3, q = bid >> 2;
    if(tid < 256) amL[tid] = Am[b*256 + tid];
    if(gbPrev) ((float*)glS4)[tid] = gbPrev[b*512 + tid];
    __syncthreads();
    // SAm (redundant per wave, deterministic tree)
    float sp = amL[lane] + amL[lane+64] + amL[lane+128] + amL[lane+192];
    #pragma unroll
    for(int off=32; off; off>>=1) sp += __shfl_xor(sp, off);
    float SAm = sp;
    // phase 1: xm[kg] = sum_j xp[kg][j]*Am[j], xp = lrelu(g*h+beta) inline
    const float4* hp = h2prev + (size_t)(b*64)*256;
    #pragma unroll
    for(int p=0;p<8;p++){
      int kg = wv*8 + p;
      float4 acc = {0.f,0.f,0.f,0.f};
      if(gbPrev){
        float4 g4 = glS4[kg];
        float4 t4 = glS4[64 + kg];
        #pragma unroll
        for(int jj=0;jj<4;jj++){
          int j = jj*64 + lane;
          float4 h = hp[kg*256 + j];
          float a = amL[j];
          acc.x += a*lrelu(g4.x*h.x + t4.x);
          acc.y += a*lrelu(g4.y*h.y + t4.y);
          acc.z += a*lrelu(g4.z*h.z + t4.z);
          acc.w += a*lrelu(g4.w*h.w + t4.w);
        }
      } else {
        #pragma unroll
        for(int jj=0;jj<4;jj++){
          int j = jj*64 + lane;
          float4 h = hp[kg*256 + j];
          float a = amL[j];
          acc.x += a*h.x; acc.y += a*h.y; acc.z += a*h.z; acc.w += a*h.w;
        }
      }
      #pragma unroll
      for(int off=32; off; off>>=1){
        acc.x += __shfl_xor(acc.x,off); acc.y += __shfl_xor(acc.y,off);
        acc.z += __shfl_xor(acc.z,off); acc.w += __shfl_xor(acc.w,off);
      }
      if(lane==0) xm4[kg] = acc;
    }
    __syncthreads();
    // phase 2: m[c] = sc*dot(W[c,:], xm) + bb[c]*SAm
    float4 xmv = xm4[lane];
    for(int r=0;r<32;r++){
      int c = wv*32 + r;
      float4 w4 = ((const float4*)(bw + c*GCH))[lane];
      float pd = w4.x*xmv.x + w4.y*xmv.y + w4.z*xmv.z + w4.w*xmv.w;
      #pragma unroll
      for(int off=32; off; off>>=1) pd += __shfl_xor(pd,off);
      if(lane==0) ((float*)mL4)[c] = sc*pd + bb[c]*SAm;
    }
    __syncthreads();
    // phase 3: s1[row] = lrelu(sc*dot(a1w[row,:], m) + a1b)
    float4 mv = mL4[lane];
    for(int r=0;r<64;r++){
      int row = wv*64 + r;
      float4 w4 = ((const float4*)(a1w + row*GCH))[lane];
      float pd = w4.x*mv.x + w4.y*mv.y + w4.z*mv.z + w4.w*mv.w;
      #pragma unroll
      for(int off=32; off; off>>=1) pd += __shfl_xor(pd,off);
      if(lane==0) ((float*)s1L4)[row] = lrelu(sc*pd + a1b[row]);
    }
    __syncthreads();
    // phase 4: gamma/beta rows t in {q*32..q*32+31} u {256+q*32..}
    float4 sa = s1L4[lane*2];
    float4 sb = s1L4[lane*2+1];
    for(int r=0;r<8;r++){
      int lr = wv*8 + r;
      int t = (lr < 32) ? (q*32 + lr) : (256 + q*32 + (lr-32));
      const float4* ar = (const float4*)(a2w + t*512);
      float4 wa = ar[lane*2], wb4 = ar[lane*2+1];
      float pd = wa.x*sa.x+wa.y*sa.y+wa.z*sa.z+wa.w*sa.w
               + wb4.x*sb.x+wb4.y*sb.y+wb4.z*sb.z+wb4.w*sb.w;
      #pragma unroll
      for(int off=32; off; off>>=1) pd += __shfl_xor(pd,off);
      if(lane==0) gbNext[b*512 + t] = sc2*pd + a2b[t];
    }
  } else {
    // ======== gemm role: 4 channels, inline AdaIN apply, K-split ========
    __shared__ float4 wl4[4][64];
    __shared__ float4 glG4[128];
    __shared__ float ps[8][260];
    __shared__ float4 h1l4[4][66];
    int idx = bid - 32;
    int c0 = (idx >> 2)*4;
    int b  = idx & 3;
    int j  = tid & 255;
    int h  = tid >> 8;
    for(int t = tid; t < 1024; t += 512){
      int row = t >> 8, jj = t & 255;
      ((float*)&wl4[row][0])[jj] = bw[(c0+row)*GCH + jj];
    }
    if(gbPrev) ((float*)glG4)[tid] = gbPrev[b*512 + tid];
    __syncthreads();
    {
      const float4* xb = h2prev + (size_t)(b*64 + h*32)*256 + j;
      float a0=0.f, a1=0.f, a2=0.f, a3=0.f;
      if(gbPrev){
        #pragma unroll 8
        for(int kg=0; kg<32; kg++){
          float4 x = xb[kg*256];
          int kga = h*32 + kg;
          float4 g4 = glG4[kga];
          float4 t4 = glG4[64 + kga];
          x.x = lrelu(g4.x*x.x + t4.x);
          x.y = lrelu(g4.y*x.y + t4.y);
          x.z = lrelu(g4.z*x.z + t4.z);
          x.w = lrelu(g4.w*x.w + t4.w);
          float4 w0 = wl4[0][kga];
          float4 w1v= wl4[1][kga];
          float4 w2v= wl4[2][kga];
          float4 w3 = wl4[3][kga];
          a0 += w0.x*x.x + w0.y*x.y + w0.z*x.z + w0.w*x.w;
          a1 += w1v.x*x.x + w1v.y*x.y + w1v.z*x.z + w1v.w*x.w;
          a2 += w2v.x*x.x + w2v.y*x.y + w2v.z*x.z + w2v.w*x.w;
          a3 += w3.x*x.x + w3.y*x.y + w3.z*x.z + w3.w*x.w;
        }
      } else {
        #pragma unroll 8
        for(int kg=0; kg<32; kg++){
          float4 x = xb[kg*256];
          int kga = h*32 + kg;
          float4 w0 = wl4[0][kga];
          float4 w1v= wl4[1][kga];
          float4 w2v= wl4[2][kga];
          float4 w3 = wl4[3][kga];
          a0 += w0.x*x.x + w0.y*x.y + w0.z*x.z + w0.w*x.w;
          a1 += w1v.x*x.x + w1v.y*x.y + w1v.z*x.z + w1v.w*x.w;
          a2 += w2v.x*x.x + w2v.y*x.y + w2v.z*x.z + w2v.w*x.w;
          a3 += w3.x*x.x + w3.y*x.y + w3.z*x.z + w3.w*x.w;
        }
      }
      ps[0+h][j] = a0; ps[2+h][j] = a1; ps[4+h][j] = a2; ps[6+h][j] = a3;
    }
    __syncthreads();
    if(tid < 256){
      #pragma unroll
      for(int ch=0;ch<4;ch++){
        float vv = (ps[ch*2][tid] + ps[ch*2+1][tid])*sc + bb[c0+ch];
        ((float*)&h1l4[ch][0])[tid] = vv;
      }
    }
    __syncthreads();
    {
      const float4* ab = At2 + (size_t)(b*64 + h*32)*256 + j;
      float r0=0.f, r1=0.f, r2=0.f, r3=0.f;
      #pragma unroll 8
      for(int kg=0; kg<32; kg++){
        float4 a  = ab[kg*256];
        float4 h0 = h1l4[0][h*32+kg];
        float4 h1 = h1l4[1][h*32+kg];
        float4 h2v= h1l4[2][h*32+kg];
        float4 h3 = h1l4[3][h*32+kg];
        r0 += a.x*h0.x + a.y*h0.y + a.z*h0.z + a.w*h0.w;
        r1 += a.x*h1.x + a.y*h1.y + a.z*h1.z + a.w*h1.w;
        r2 += a.x*h2v.x + a.y*h2v.y + a.z*h2v.z + a.w*h2v.w;
        r3 += a.x*h3.x + a.y*h3.y + a.z*h3.z + a.w*h3.w;
      }
      ps[0+h][j] = r0; ps[2+h][j] = r1; ps[4+h][j] = r2; ps[6+h][j] = r3;
    }
    __syncthreads();
    if(tid < 256){
      float4 o;
      o.x = ps[0][tid]+ps[1][tid];
      o.y = ps[2][tid]+ps[3][tid];
      o.z = ps[4][tid]+ps[5][tid];
      o.w = ps[6][tid]+ps[7][tid];
      h2next[(size_t)(b*64 + (c0>>2))*256 + tid] = o;
    }
  }
}

// ---- v: final AdaIN applied inline during LDS staging ----
__global__ __launch_bounds__(256) void k_v(const float4* __restrict__ h2f,
        const float* __restrict__ gbF,
        const float4* __restrict__ wT4, float4* __restrict__ v4){
  int s0 = blockIdx.x*16;           // grid (16,9,4)
  int k  = blockIdx.y;
  int b  = blockIdx.z;
  int tid = threadIdx.x;
  __shared__ float4 glV4[128];
  __shared__ float4 wl[64][33];
  __shared__ float xft[256][17];
  ((float*)glV4)[tid] = gbF[b*512 + tid];
  ((float*)glV4)[256+tid] = gbF[b*512 + 256 + tid];
  __syncthreads();
  for(int t = tid; t < 1024; t += 256){
    int cg = t >> 4, si = t & 15;
    float4 xv = h2f[(size_t)(b*64 + cg)*256 + s0 + si];
    float4 g4 = glV4[cg];
    float4 t4 = glV4[64 + cg];
    xft[cg*4+0][si] = lrelu(g4.x*xv.x + t4.x);
    xft[cg*4+1][si] = lrelu(g4.y*xv.y + t4.y);
    xft[cg*4+2][si] = lrelu(g4.z*xv.z + t4.z);
    xft[cg*4+3][si] = lrelu(g4.w*xv.w + t4.w);
  }
  int og = tid & 31, sh = tid >> 5;  // sh 0..7
  const float4* wb = wT4 + (size_t)k*GCH*32;
  float4 a0 = {0.f,0.f,0.f,0.f}, a1 = {0.f,0.f,0.f,0.f};
  for(int ct=0; ct<4; ct++){
    __syncthreads();
    for(int t = tid; t < 2048; t += 256){
      int cc = t>>5, o = t&31;
      wl[cc][o] = wb[(ct*64+cc)*32 + o];
    }
    __syncthreads();
    #pragma unroll 4
    for(int cc=0;cc<64;cc++){
      float4 w = wl[cc][og];
      int c = ct*64+cc;
      float x0v = xft[c][sh];
      float x1v = xft[c][8+sh];
      a0.x += w.x*x0v; a0.y += w.y*x0v; a0.z += w.z*x0v; a0.w += w.w*x0v;
      a1.x += w.x*x1v; a1.y += w.y*x1v; a1.z += w.z*x1v; a1.w += w.w*x1v;
    }
  }
  size_t base = (size_t)(b*9+k)*SS + s0;
  v4[(base + sh)*32 + og]     = a0;
  v4[(base + 8 + sh)*32 + og] = a1;
}

// ---- fused conv1-gather(paired float4) + conv2 (scalar weights), 8x8 tile ----
__global__ __launch_bounds__(256) void k_conv(const float4* __restrict__ v4,
        const int* __restrict__ seg, const float4* __restrict__ b14,
        const float* __restrict__ w2t, float* __restrict__ y2){
  __shared__ float4 y1t4[100*9];    // [pp][8 ch-f4 + pad]
  __shared__ int   segl[144];
  __shared__ float part[768];
  int bid = blockIdx.x;
  int x = bid & 7;
  int b = x >> 1;
  int sub = ((bid >> 3) << 1) + (x & 1);  // 0..4095
  int g = sub & 3;
  int tile = sub >> 2;
  int x0p = (tile & 31)*8, y0p = (tile >> 5)*8;
  int tid = threadIdx.x;
  if(tid < 144){
    int r = tid/12, cc = tid%12;
    int gy = y0p - 2 + r, gx = x0p - 2 + cc;
    segl[tid] = (gy>=0 && gy<256 && gx>=0 && gx<256) ? seg[(b*256+gy)*256+gx] : -1;
  }
  __syncthreads();
  int o2 = tid & 3;                 // pair index: channels-f4 {o2*2, o2*2+1}
  const float4* vb = v4 + (size_t)(b*9)*SS*32 + g*8 + o2*2;
  float4 biasA = b14[g*8 + o2*2];
  float4 biasB = b14[g*8 + o2*2 + 1];
  bool interior = (x0p >= 8 && x0p <= 240 && y0p >= 8 && y0p <= 240);
  if(interior){
    for(int task = tid; task < 400; task += 256){
      int pp = task >> 2;
      int py = pp/10, px = pp - py*10;
      float4 aA = biasA, aB = biasB;
      #pragma unroll
      for(int k=0;k<9;k++){
        int sidx = segl[(py + k/3)*12 + (px + k%3)];
        const float4* pv = vb + (k*SS + sidx)*32;
        float4 vA = pv[0], vB = pv[1];
        aA.x += vA.x; aA.y += vA.y; aA.z += vA.z; aA.w += vA.w;
        aB.x += vB.x; aB.y += vB.y; aB.z += vB.z; aB.w += vB.w;
      }
      float4 valA, valB;
      valA.x = lrelu(aA.x); valA.y = lrelu(aA.y); valA.z = lrelu(aA.z); valA.w = lrelu(aA.w);
      valB.x = lrelu(aB.x); valB.y = lrelu(aB.y); valB.z = lrelu(aB.z); valB.w = lrelu(aB.w);
      y1t4[pp*9 + o2*2]     = valA;
      y1t4[pp*9 + o2*2 + 1] = valB;
    }
  } else {
    for(int task = tid; task < 400; task += 256){
      int pp = task >> 2;
      int py = pp/10, px = pp - py*10;
      int gy = y0p - 1 + py, gx = x0p - 1 + px;
      bool pix_ok = (gy>=0 && gy<256 && gx>=0 && gx<256);
      float4 aA = biasA, aB = biasB;
      #pragma unroll
      for(int k=0;k<9;k++){
        int sidx = segl[(py + k/3)*12 + (px + k%3)];
        int sidx0 = sidx < 0 ? 0 : sidx;
        float msk = sidx < 0 ? 0.f : 1.f;
        const float4* pv = vb + (k*SS + sidx0)*32;
        float4 vA = pv[0], vB = pv[1];
        aA.x += msk*vA.x; aA.y += msk*vA.y; aA.z += msk*vA.z; aA.w += msk*vA.w;
        aB.x += msk*vB.x; aB.y += msk*vB.y; aB.z += msk*vB.z; aB.w += msk*vB.w;
      }
      float4 valA, valB;
      valA.x = pix_ok ? lrelu(aA.x) : 0.f;
      valA.y = pix_ok ? lrelu(aA.y) : 0.f;
      valA.z = pix_ok ? lrelu(aA.z) : 0.f;
      valA.w = pix_ok ? lrelu(aA.w) : 0.f;
      valB.x = pix_ok ? lrelu(aB.x) : 0.f;
      valB.y = pix_ok ? lrelu(aB.y) : 0.f;
      valB.z = pix_ok ? lrelu(aB.z) : 0.f;
      valB.w = pix_ok ? lrelu(aB.w) : 0.f;
      y1t4[pp*9 + o2*2]     = valA;
      y1t4[pp*9 + o2*2 + 1] = valB;
    }
  }
  __syncthreads();
  int pxo = tid & 63, sg = tid >> 6;
  int sgu = __builtin_amdgcn_readfirstlane(sg);
  const float* wk0 = w2t + (g*4 + sgu)*24;   // + k*384
  int ty = pxo >> 3, tx = pxo & 7;
  float p0=0.f,p1=0.f,p2=0.f;
  #pragma unroll
  for(int k=0;k<9;k++){
    int pp0 = (ty + k/3)*10 + (tx + k%3);
    float4 ya = y1t4[pp0*9 + sgu*2];
    float4 yb = y1t4[pp0*9 + sgu*2 + 1];
    const float* wk = wk0 + k*384;
    p0 += wk[0]*ya.x + wk[1]*ya.y + wk[2]*ya.z + wk[3]*ya.w
        + wk[4]*yb.x + wk[5]*yb.y + wk[6]*yb.z + wk[7]*yb.w;
    p1 += wk[8]*ya.x + wk[9]*ya.y + wk[10]*ya.z + wk[11]*ya.w
        + wk[12]*yb.x + wk[13]*yb.y + wk[14]*yb.z + wk[15]*yb.w;
    p2 += wk[16]*ya.x + wk[17]*ya.y + wk[18]*ya.z + wk[19]*ya.w
        + wk[20]*yb.x + wk[21]*yb.y + wk[22]*yb.z + wk[23]*yb.w;
  }
  part[tid]     = p0;
  part[256+tid] = p1;
  part[512+tid] = p2;
  __syncthreads();
  if(tid < 64){
    float s0 = part[tid]    +part[tid+64]    +part[tid+128]    +part[tid+192];
    float s1 = part[256+tid]+part[256+tid+64]+part[256+tid+128]+part[256+tid+192];
    float s2 = part[512+tid]+part[512+tid+64]+part[512+tid+128]+part[512+tid+192];
    int gy = y0p + (tid>>3), gx = x0p + (tid&7);
    int nidx = gy*256+gx;
    atomicAdd(&y2[(b*3+0)*NPIX+nidx], s0);
    atomicAdd(&y2[(b*3+1)*NPIX+nidx], s1);
    atomicAdd(&y2[(b*3+2)*NPIX+nidx], s2);
  }
}

// ---- per (b,channel) sum & sumsq, parallel chunks with f64 atomics ----
__global__ void k_stats(const float* __restrict__ y2, double* __restrict__ stats){
  int bc = blockIdx.x;     // 12
  int chunk = blockIdx.y;  // 8
  const float* p = y2 + (size_t)bc*NPIX + chunk*8192;
  int t = threadIdx.x;
  double s=0.0, q=0.0;
  for(int i=t;i<8192;i+=256){ double vv = (double)p[i]; s+=vv; q+=vv*vv; }
  __shared__ double rs[256], rq[256];
  rs[t]=s; rq[t]=q; __syncthreads();
  for(int st=128; st; st>>=1){ if(t<st){rs[t]+=rs[t+st]; rq[t]+=rq[t+st];} __syncthreads(); }
  if(t==0){ atomicAdd(&stats[bc*2], rs[0]); atomicAdd(&stats[bc*2+1], rq[0]); }
}

// ---- instance norm + tanh ----
__global__ void k_norm(const float* __restrict__ y2, const double* __restrict__ stats,
                       float* __restrict__ out){
  int bu = (blockIdx.x*256) >> 16;           // uniform per block
  double mu  = stats[bu*2+0] * (1.0/65536.0);
  double ex2 = stats[bu*2+1] * (1.0/65536.0);
  double var = ex2 - mu*mu;
  float inv = (float)(1.0/sqrt(var + 1e-5));
  float mf = (float)mu;
  int idx = blockIdx.x*256+threadIdx.x;
  out[idx] = tanhf((y2[idx]-mf)*inv);
}

extern "C" void kernel_launch(void* const* d_in, const int* in_sizes, int n_in,
                              void* d_out, int out_size, void* d_ws, size_t ws_size,
                              hipStream_t stream) {
  const float* z   = (const float*)d_in[0];
  const float* img = (const float*)d_in[1];
  const int*   seg = (const int*)d_in[2];
  const float* A   = (const float*)d_in[3];
  const float* pw  = (const float*)d_in[4];
  const float* pb  = (const float*)d_in[5];
  const float* bw  = (const float*)d_in[6];
  const float* bb  = (const float*)d_in[7];
  const float* a1w = (const float*)d_in[8];
  const float* a1b = (const float*)d_in[9];
  const float* a2w = (const float*)d_in[10];
  const float* a2b = (const float*)d_in[11];
  const float* w1  = (const float*)d_in[12];
  const float* b1  = (const float*)d_in[13];
  const float* w2  = (const float*)d_in[14];
  const float* b2  = (const float*)d_in[15]; (void)b2; // cancels under InstanceNorm
  float* out = (float*)d_out;

  float* ws = (float*)d_ws;
  float* segsum = ws;                    // 3072
  float* counts = ws + 3072;             // 1024 -> 4096
  float* Am     = ws + 4096;             // 1024 -> 5120
  double* stats = (double*)(ws + 5120);  // 24 doubles -> 5168, pad to 5248
  float* gb0 = ws + 5248;                // 2048
  float* gb1 = gb0 + 2048;               // 2048 -> 9344
  float* h2a = ws + 9344;                // 262144
  float* h2b = h2a + 262144;             // 262144
  float* At2 = h2b + 262144;             // 262144
  float* wT  = At2 + 262144;             // 294912
  float* v   = wT + 294912;              // 1179648
  float* y2  = v + 1179648;              // 786432
  float* w2t = y2 + 786432;              // 3456   (end ~12.2 MB)

  hipMemsetAsync(ws, 0, 5248*sizeof(float), stream);     // sums + stats
  hipMemsetAsync(y2, 0, 786432*sizeof(float), stream);   // conv2 accumulator

  float sProj = (float)sqrt(2.0/131.0);
  float s256  = (float)sqrt(2.0/256.0);
  float s512  = (float)sqrt(2.0/512.0);

  k_pp  <<<516 + 1166, 256, 0, stream>>>(img, seg, segsum, counts,
                                         A, w1, w2, At2, Am, wT, w2t);
  k_x0  <<<dim3(64,4), 256, 0, stream>>>(segsum, counts, z, pw, pb, sProj,
                                         (float4*)h2a);

  for(int blk=0; blk<NBLKS; blk++){
    const float* h2p = (blk & 1) ? h2b : h2a;
    float*       h2n = (blk & 1) ? h2a : h2b;
    const float* gbp = (blk == 0) ? (const float*)nullptr
                                  : ((blk & 1) ? gb0 : gb1);
    float*       gbn = (blk & 1) ? gb1 : gb0;
    k_iter<<<288, 512, 0, stream>>>((const float4*)h2p, gbp,
                                    (float4*)h2n, gbn,
                                    bw + blk*GCH*GCH, bb + blk*GCH,
                                    a1w + blk*512*GCH, a1b + blk*512,
                                    a2w + blk*512*512, a2b + blk*512,
                                    (const float4*)At2, Am, s256, s512);
  }
  // after 8 iters: final h2 in h2a (blk=7 wrote h2a), final gb in gb1

  k_v   <<<dim3(16,9,4), 256, 0, stream>>>((const float4*)h2a, gb1,
                                           (const float4*)wT, (float4*)v);
  k_conv<<<16384, 256, 0, stream>>>((const float4*)v, seg, (const float4*)b1, w2t, y2);
  k_stats<<<dim3(12,8), 256, 0, stream>>>(y2, stats);
  k_norm<<<3072, 256, 0, stream>>>(y2, stats, out);
}

// Round 13
// 401.615 us; speedup vs baseline: 1.7038x; 1.7038x over previous
//
#include <hip/hip_runtime.h>
#include <cmath>

#define BB 4
#define SS 256
#define ZDIM 128
#define GCH 256
#define NBLKS 8
#define NPIX 65536   // 256*256
#define U1C 128      // GC/2

__device__ __forceinline__ float lrelu(float x){ return x >= 0.f ? x : 0.2f*x; }

// ---- fused prep: pool(0..255) + A transpose(256..511) + Am(512..515) + w ----
__global__ __launch_bounds__(256) void k_pp(const float* __restrict__ img,
        const int* __restrict__ seg, float* __restrict__ segsum,
        float* __restrict__ counts, const float* __restrict__ A,
        const float* __restrict__ w1, const float* __restrict__ w2,
        float* __restrict__ At2, float* __restrict__ Am,
        float* __restrict__ wT, float* __restrict__ w2t){
  int bid = blockIdx.x;
  int tid = threadIdx.x;
  if(bid < 256){
    __shared__ float ls[SS*4];
    for(int j=tid;j<SS*4;j+=256) ls[j]=0.f;
    __syncthreads();
    int b = bid >> 6;
    int base = bid*1024;
    for(int it=0; it<4; it++){
      int idx = base + it*256 + tid;
      int n = idx & (NPIX-1);
      int s = seg[idx];
      atomicAdd(&ls[s*4+0], img[(b*3+0)*NPIX+n]);
      atomicAdd(&ls[s*4+1], img[(b*3+1)*NPIX+n]);
      atomicAdd(&ls[s*4+2], img[(b*3+2)*NPIX+n]);
      atomicAdd(&ls[s*4+3], 1.0f);
    }
    __syncthreads();
    for(int j=tid;j<SS*4;j+=256){
      int s = j>>2, c = j&3;
      float vv = ls[j];
      if(vv != 0.f){
        if(c<3) atomicAdd(&segsum[(b*SS+s)*3+c], vv);
        else    atomicAdd(&counts[b*SS+s], vv);
      }
    }
  } else if(bid < 512){
    __shared__ float t[32][33];
    int sb = bid - 256;
    int b = sb >> 6;
    int bx = (sb & 7)*32, by = ((sb >> 3) & 7)*32;
    int lx = tid & 31, ly4 = (tid >> 5)*4;
    #pragma unroll
    for(int r=0;r<4;r++)
      t[ly4+r][lx] = A[(b<<16) + ((by+ly4+r)<<8) + bx + lx];
    __syncthreads();
    #pragma unroll
    for(int r=0;r<4;r++){
      int jj = bx + ly4 + r;
      int i  = by + lx;
      At2[(b<<16) + ((jj>>2)<<10) + (i<<2) + (jj&3)] = t[lx][ly4+r];
    }
  } else if(bid < 516){
    // Am[b][j] = (1/256) sum_i A[b][i][j]  (deterministic fixed-order sweep)
    int b = bid - 512;
    int j = tid;
    float s0=0.f,s1=0.f,s2=0.f,s3=0.f;
    for(int i=0;i<256;i+=4){
      s0 += A[(b<<16)+((i+0)<<8)+j];
      s1 += A[(b<<16)+((i+1)<<8)+j];
      s2 += A[(b<<16)+((i+2)<<8)+j];
      s3 += A[(b<<16)+((i+3)<<8)+j];
    }
    Am[b*256+j] = ((s0+s1)+(s2+s3))*(1.f/256.f);
  } else {
    int idx = (bid-516)*256 + tid;
    if(idx < 294912){
      int o = idx & 127; int r = idx >> 7; int c = r & 255; int k = r >> 8;
      wT[idx] = w1[(o*GCH + c)*9 + k];
    } else if(idx < 294912 + 3456){
      int t2 = idx - 294912;
      int cc = t2 & 7;
      int oc = (t2 >> 3) % 3;
      int sg = (t2 / 24) & 3;
      int g  = (t2 / 96) & 3;
      int k  = t2 / 384;
      w2t[t2] = w2[oc*1152 + (g*32 + sg*8 + cc)*9 + k];
    }
  }
}

// ---- x0 = WSproj(concat(feats, z)) -> h2a (packed float4 over channels) ----
__global__ __launch_bounds__(256) void k_x0(const float* __restrict__ segsum,
        const float* __restrict__ counts, const float* __restrict__ z,
        const float* __restrict__ pw, const float* __restrict__ pb,
        float sc, float4* __restrict__ xp2){
  int og = blockIdx.x;              // 0..63 (channel group of 4)
  int b  = blockIdx.y;
  int i  = threadIdx.x;             // node
  float cnt = counts[b*SS+i] + 1e-6f;
  float f0 = segsum[(b*SS+i)*3+0]/cnt;
  float f1 = segsum[(b*SS+i)*3+1]/cnt;
  float f2 = segsum[(b*SS+i)*3+2]/cnt;
  const float* zb = z + b*ZDIM;
  float vals[4];
  #pragma unroll
  for(int oo=0;oo<4;oo++){
    int o = og*4 + oo;
    const float* wr = pw + o*131;
    float acc = wr[0]*f0 + wr[1]*f1 + wr[2]*f2;
    #pragma unroll 8
    for(int j=0;j<ZDIM;j++) acc += wr[3+j]*zb[j];
    vals[oo] = acc*sc + pb[o];
  }
  float4 o4 = {vals[0], vals[1], vals[2], vals[3]};
  xp2[(b*64+og)*256 + i] = o4;
}

// ---- one graph iteration in ONE launch: style(bid 0..31) || gemm(32..287) ----
// Both roles read only (h2prev, gbPrev); no intra-launch dependency.
__global__ __launch_bounds__(512) void k_iter(
    const float4* __restrict__ h2prev, const float* __restrict__ gbPrev,
    float4* __restrict__ h2next, float* __restrict__ gbNext,
    const float* __restrict__ bw, const float* __restrict__ bb,
    const float* __restrict__ a1w, const float* __restrict__ a1b,
    const float* __restrict__ a2w, const float* __restrict__ a2b,
    const float4* __restrict__ At2, const float* __restrict__ Am,
    float sc, float sc2){
  int bid = blockIdx.x;
  int tid = threadIdx.x;
  int lane = tid & 63, wv = tid >> 6;
  if(bid < 32){
    // ======== style role: q-th 1/8 of gamma/beta rows for batch b ========
    __shared__ float amL[256];
    __shared__ float4 glS4[128];
    __shared__ float4 xm4[64];
    __shared__ float mL[256];
    __shared__ float s1L[512];
    int b = bid & 3, q = bid >> 2;
    if(tid < 256) amL[tid] = Am[b*256 + tid];
    if(gbPrev) ((float*)glS4)[tid] = gbPrev[b*512 + tid];
    __syncthreads();
    // SAm (redundant per wave, deterministic tree)
    float sp = amL[lane] + amL[lane+64] + amL[lane+128] + amL[lane+192];
    #pragma unroll
    for(int off=32; off; off>>=1) sp += __shfl_xor(sp, off);
    float SAm = sp;
    // phase 1: xm[kg] = sum_j xp[kg][j]*Am[j], xp = lrelu(g*h+beta) inline
    const float4* hp = h2prev + (size_t)(b*64)*256;
    #pragma unroll
    for(int p=0;p<8;p++){
      int kg = wv*8 + p;
      float4 acc = {0.f,0.f,0.f,0.f};
      if(gbPrev){
        float4 g4 = glS4[kg];
        float4 t4 = glS4[64 + kg];
        #pragma unroll
        for(int jj=0;jj<4;jj++){
          int j = jj*64 + lane;
          float4 h = hp[kg*256 + j];
          float a = amL[j];
          acc.x += a*lrelu(g4.x*h.x + t4.x);
          acc.y += a*lrelu(g4.y*h.y + t4.y);
          acc.z += a*lrelu(g4.z*h.z + t4.z);
          acc.w += a*lrelu(g4.w*h.w + t4.w);
        }
      } else {
        #pragma unroll
        for(int jj=0;jj<4;jj++){
          int j = jj*64 + lane;
          float4 h = hp[kg*256 + j];
          float a = amL[j];
          acc.x += a*h.x; acc.y += a*h.y; acc.z += a*h.z; acc.w += a*h.w;
        }
      }
      #pragma unroll
      for(int off=32; off; off>>=1){
        acc.x += __shfl_xor(acc.x,off); acc.y += __shfl_xor(acc.y,off);
        acc.z += __shfl_xor(acc.z,off); acc.w += __shfl_xor(acc.w,off);
      }
      if(lane==0) xm4[kg] = acc;
    }
    __syncthreads();
    // phase 2: m[c] = sc*dot(W[c,:], xm) + bb[c]*SAm  (4 rows in flight)
    float4 xmv = xm4[lane];
    #pragma unroll 2
    for(int pass=0; pass<8; pass++){
      int c = wv*32 + pass*4;
      float4 wA = ((const float4*)(bw + (c+0)*GCH))[lane];
      float4 wB = ((const float4*)(bw + (c+1)*GCH))[lane];
      float4 wC = ((const float4*)(bw + (c+2)*GCH))[lane];
      float4 wD = ((const float4*)(bw + (c+3)*GCH))[lane];
      float pA = wA.x*xmv.x + wA.y*xmv.y + wA.z*xmv.z + wA.w*xmv.w;
      float pB = wB.x*xmv.x + wB.y*xmv.y + wB.z*xmv.z + wB.w*xmv.w;
      float pC = wC.x*xmv.x + wC.y*xmv.y + wC.z*xmv.z + wC.w*xmv.w;
      float pD = wD.x*xmv.x + wD.y*xmv.y + wD.z*xmv.z + wD.w*xmv.w;
      #pragma unroll
      for(int off=32; off; off>>=1){
        pA += __shfl_xor(pA,off); pB += __shfl_xor(pB,off);
        pC += __shfl_xor(pC,off); pD += __shfl_xor(pD,off);
      }
      if(lane==0){
        mL[c+0] = sc*pA + bb[c+0]*SAm;
        mL[c+1] = sc*pB + bb[c+1]*SAm;
        mL[c+2] = sc*pC + bb[c+2]*SAm;
        mL[c+3] = sc*pD + bb[c+3]*SAm;
      }
    }
    __syncthreads();
    // phase 3: s1[row] = lrelu(sc*dot(a1w[row,:], m) + a1b)  (4 rows in flight)
    float4 mv = ((const float4*)mL)[lane];
    #pragma unroll 2
    for(int pass=0; pass<16; pass++){
      int row = wv*64 + pass*4;
      float4 wA = ((const float4*)(a1w + (row+0)*GCH))[lane];
      float4 wB = ((const float4*)(a1w + (row+1)*GCH))[lane];
      float4 wC = ((const float4*)(a1w + (row+2)*GCH))[lane];
      float4 wD = ((const float4*)(a1w + (row+3)*GCH))[lane];
      float pA = wA.x*mv.x + wA.y*mv.y + wA.z*mv.z + wA.w*mv.w;
      float pB = wB.x*mv.x + wB.y*mv.y + wB.z*mv.z + wB.w*mv.w;
      float pC = wC.x*mv.x + wC.y*mv.y + wC.z*mv.z + wC.w*mv.w;
      float pD = wD.x*mv.x + wD.y*mv.y + wD.z*mv.z + wD.w*mv.w;
      #pragma unroll
      for(int off=32; off; off>>=1){
        pA += __shfl_xor(pA,off); pB += __shfl_xor(pB,off);
        pC += __shfl_xor(pC,off); pD += __shfl_xor(pD,off);
      }
      if(lane==0){
        s1L[row+0] = lrelu(sc*pA + a1b[row+0]);
        s1L[row+1] = lrelu(sc*pB + a1b[row+1]);
        s1L[row+2] = lrelu(sc*pC + a1b[row+2]);
        s1L[row+3] = lrelu(sc*pD + a1b[row+3]);
      }
    }
    __syncthreads();
    // phase 4: 64 gamma/beta rows of this q-slice (4 rows in flight)
    float4 sa = ((const float4*)s1L)[lane*2];
    float4 sb = ((const float4*)s1L)[lane*2+1];
    #pragma unroll
    for(int pass=0; pass<2; pass++){
      int lr0 = wv*8 + pass*4;
      float pR[4];
      #pragma unroll
      for(int r=0;r<4;r++){
        int lr = lr0 + r;
        int t = (lr < 32) ? (q*32 + lr) : (256 + q*32 + (lr-32));
        const float4* ar = (const float4*)(a2w + t*512);
        float4 wa = ar[lane*2], wb4 = ar[lane*2+1];
        pR[r] = wa.x*sa.x+wa.y*sa.y+wa.z*sa.z+wa.w*sa.w
              + wb4.x*sb.x+wb4.y*sb.y+wb4.z*sb.z+wb4.w*sb.w;
      }
      #pragma unroll
      for(int off=32; off; off>>=1){
        pR[0]+=__shfl_xor(pR[0],off); pR[1]+=__shfl_xor(pR[1],off);
        pR[2]+=__shfl_xor(pR[2],off); pR[3]+=__shfl_xor(pR[3],off);
      }
      if(lane==0){
        #pragma unroll
        for(int r=0;r<4;r++){
          int lr = lr0 + r;
          int t = (lr < 32) ? (q*32 + lr) : (256 + q*32 + (lr-32));
          gbNext[b*512 + t] = sc2*pR[r] + a2b[t];
        }
      }
    }
  } else {
    // ======== gemm role: 4 channels, inline AdaIN apply, K-split ========
    __shared__ float4 wl4[4][64];
    __shared__ float4 glG4[128];
    __shared__ float ps[8][260];
    __shared__ float4 h1l4[4][66];
    int idx = bid - 32;
    int c0 = (idx >> 2)*4;
    int b  = idx & 3;
    int j  = tid & 255;
    int h  = tid >> 8;
    for(int t = tid; t < 1024; t += 512){
      int row = t >> 8, jj = t & 255;
      ((float*)&wl4[row][0])[jj] = bw[(c0+row)*GCH + jj];
    }
    if(gbPrev) ((float*)glG4)[tid] = gbPrev[b*512 + tid];
    __syncthreads();
    {
      const float4* xb = h2prev + (size_t)(b*64 + h*32)*256 + j;
      float a0=0.f, a1=0.f, a2=0.f, a3=0.f;
      if(gbPrev){
        #pragma unroll 8
        for(int kg=0; kg<32; kg++){
          float4 x = xb[kg*256];
          int kga = h*32 + kg;
          float4 g4 = glG4[kga];
          float4 t4 = glG4[64 + kga];
          x.x = lrelu(g4.x*x.x + t4.x);
          x.y = lrelu(g4.y*x.y + t4.y);
          x.z = lrelu(g4.z*x.z + t4.z);
          x.w = lrelu(g4.w*x.w + t4.w);
          float4 w0 = wl4[0][kga];
          float4 w1v= wl4[1][kga];
          float4 w2v= wl4[2][kga];
          float4 w3 = wl4[3][kga];
          a0 += w0.x*x.x + w0.y*x.y + w0.z*x.z + w0.w*x.w;
          a1 += w1v.x*x.x + w1v.y*x.y + w1v.z*x.z + w1v.w*x.w;
          a2 += w2v.x*x.x + w2v.y*x.y + w2v.z*x.z + w2v.w*x.w;
          a3 += w3.x*x.x + w3.y*x.y + w3.z*x.z + w3.w*x.w;
        }
      } else {
        #pragma unroll 8
        for(int kg=0; kg<32; kg++){
          float4 x = xb[kg*256];
          int kga = h*32 + kg;
          float4 w0 = wl4[0][kga];
          float4 w1v= wl4[1][kga];
          float4 w2v= wl4[2][kga];
          float4 w3 = wl4[3][kga];
          a0 += w0.x*x.x + w0.y*x.y + w0.z*x.z + w0.w*x.w;
          a1 += w1v.x*x.x + w1v.y*x.y + w1v.z*x.z + w1v.w*x.w;
          a2 += w2v.x*x.x + w2v.y*x.y + w2v.z*x.z + w2v.w*x.w;
          a3 += w3.x*x.x + w3.y*x.y + w3.z*x.z + w3.w*x.w;
        }
      }
      ps[0+h][j] = a0; ps[2+h][j] = a1; ps[4+h][j] = a2; ps[6+h][j] = a3;
    }
    __syncthreads();
    if(tid < 256){
      #pragma unroll
      for(int ch=0;ch<4;ch++){
        float vv = (ps[ch*2][tid] + ps[ch*2+1][tid])*sc + bb[c0+ch];
        ((float*)&h1l4[ch][0])[tid] = vv;
      }
    }
    __syncthreads();
    {
      const float4* ab = At2 + (size_t)(b*64 + h*32)*256 + j;
      float r0=0.f, r1=0.f, r2=0.f, r3=0.f;
      #pragma unroll 8
      for(int kg=0; kg<32; kg++){
        float4 a  = ab[kg*256];
        float4 h0 = h1l4[0][h*32+kg];
        float4 h1 = h1l4[1][h*32+kg];
        float4 h2v= h1l4[2][h*32+kg];
        float4 h3 = h1l4[3][h*32+kg];
        r0 += a.x*h0.x + a.y*h0.y + a.z*h0.z + a.w*h0.w;
        r1 += a.x*h1.x + a.y*h1.y + a.z*h1.z + a.w*h1.w;
        r2 += a.x*h2v.x + a.y*h2v.y + a.z*h2v.z + a.w*h2v.w;
        r3 += a.x*h3.x + a.y*h3.y + a.z*h3.z + a.w*h3.w;
      }
      ps[0+h][j] = r0; ps[2+h][j] = r1; ps[4+h][j] = r2; ps[6+h][j] = r3;
    }
    __syncthreads();
    if(tid < 256){
      float4 o;
      o.x = ps[0][tid]+ps[1][tid];
      o.y = ps[2][tid]+ps[3][tid];
      o.z = ps[4][tid]+ps[5][tid];
      o.w = ps[6][tid]+ps[7][tid];
      h2next[(size_t)(b*64 + (c0>>2))*256 + tid] = o;
    }
  }
}

// ---- v: final AdaIN applied inline during LDS staging ----
__global__ __launch_bounds__(256) void k_v(const float4* __restrict__ h2f,
        const float* __restrict__ gbF,
        const float4* __restrict__ wT4, float4* __restrict__ v4){
  int s0 = blockIdx.x*16;           // grid (16,9,4)
  int k  = blockIdx.y;
  int b  = blockIdx.z;
  int tid = threadIdx.x;
  __shared__ float4 glV4[128];
  __shared__ float4 wl[64][33];
  __shared__ float xft[256][17];
  ((float*)glV4)[tid] = gbF[b*512 + tid];
  ((float*)glV4)[256+tid] = gbF[b*512 + 256 + tid];
  __syncthreads();
  for(int t = tid; t < 1024; t += 256){
    int cg = t >> 4, si = t & 15;
    float4 xv = h2f[(size_t)(b*64 + cg)*256 + s0 + si];
    float4 g4 = glV4[cg];
    float4 t4 = glV4[64 + cg];
    xft[cg*4+0][si] = lrelu(g4.x*xv.x + t4.x);
    xft[cg*4+1][si] = lrelu(g4.y*xv.y + t4.y);
    xft[cg*4+2][si] = lrelu(g4.z*xv.z + t4.z);
    xft[cg*4+3][si] = lrelu(g4.w*xv.w + t4.w);
  }
  int og = tid & 31, sh = tid >> 5;  // sh 0..7
  const float4* wb = wT4 + (size_t)k*GCH*32;
  float4 a0 = {0.f,0.f,0.f,0.f}, a1 = {0.f,0.f,0.f,0.f};
  for(int ct=0; ct<4; ct++){
    __syncthreads();
    for(int t = tid; t < 2048; t += 256){
      int cc = t>>5, o = t&31;
      wl[cc][o] = wb[(ct*64+cc)*32 + o];
    }
    __syncthreads();
    #pragma unroll 4
    for(int cc=0;cc<64;cc++){
      float4 w = wl[cc][og];
      int c = ct*64+cc;
      float x0v = xft[c][sh];
      float x1v = xft[c][8+sh];
      a0.x += w.x*x0v; a0.y += w.y*x0v; a0.z += w.z*x0v; a0.w += w.w*x0v;
      a1.x += w.x*x1v; a1.y += w.y*x1v; a1.z += w.z*x1v; a1.w += w.w*x1v;
    }
  }
  size_t base = (size_t)(b*9+k)*SS + s0;
  v4[(base + sh)*32 + og]     = a0;
  v4[(base + 8 + sh)*32 + og] = a1;
}

// ---- fused conv1-gather(paired float4) + conv2 (scalar weights), 8x8 tile ----
__global__ __launch_bounds__(256) void k_conv(const float4* __restrict__ v4,
        const int* __restrict__ seg, const float4* __restrict__ b14,
        const float* __restrict__ w2t, float* __restrict__ y2){
  __shared__ float4 y1t4[100*9];    // [pp][8 ch-f4 + pad]
  __shared__ int   segl[144];
  __shared__ float part[768];
  int bid = blockIdx.x;
  int x = bid & 7;
  int b = x >> 1;
  int sub = ((bid >> 3) << 1) + (x & 1);  // 0..4095
  int g = sub & 3;
  int tile = sub >> 2;
  int x0p = (tile & 31)*8, y0p = (tile >> 5)*8;
  int tid = threadIdx.x;
  if(tid < 144){
    int r = tid/12, cc = tid%12;
    int gy = y0p - 2 + r, gx = x0p - 2 + cc;
    segl[tid] = (gy>=0 && gy<256 && gx>=0 && gx<256) ? seg[(b*256+gy)*256+gx] : -1;
  }
  __syncthreads();
  int o2 = tid & 3;                 // pair index: channels-f4 {o2*2, o2*2+1}
  const float4* vb = v4 + (size_t)(b*9)*SS*32 + g*8 + o2*2;
  float4 biasA = b14[g*8 + o2*2];
  float4 biasB = b14[g*8 + o2*2 + 1];
  bool interior = (x0p >= 8 && x0p <= 240 && y0p >= 8 && y0p <= 240);
  if(interior){
    for(int task = tid; task < 400; task += 256){
      int pp = task >> 2;
      int py = pp/10, px = pp - py*10;
      float4 aA = biasA, aB = biasB;
      #pragma unroll
      for(int k=0;k<9;k++){
        int sidx = segl[(py + k/3)*12 + (px + k%3)];
        const float4* pv = vb + (k*SS + sidx)*32;
        float4 vA = pv[0], vB = pv[1];
        aA.x += vA.x; aA.y += vA.y; aA.z += vA.z; aA.w += vA.w;
        aB.x += vB.x; aB.y += vB.y; aB.z += vB.z; aB.w += vB.w;
      }
      float4 valA, valB;
      valA.x = lrelu(aA.x); valA.y = lrelu(aA.y); valA.z = lrelu(aA.z); valA.w = lrelu(aA.w);
      valB.x = lrelu(aB.x); valB.y = lrelu(aB.y); valB.z = lrelu(aB.z); valB.w = lrelu(aB.w);
      y1t4[pp*9 + o2*2]     = valA;
      y1t4[pp*9 + o2*2 + 1] = valB;
    }
  } else {
    for(int task = tid; task < 400; task += 256){
      int pp = task >> 2;
      int py = pp/10, px = pp - py*10;
      int gy = y0p - 1 + py, gx = x0p - 1 + px;
      bool pix_ok = (gy>=0 && gy<256 && gx>=0 && gx<256);
      float4 aA = biasA, aB = biasB;
      #pragma unroll
      for(int k=0;k<9;k++){
        int sidx = segl[(py + k/3)*12 + (px + k%3)];
        int sidx0 = sidx < 0 ? 0 : sidx;
        float msk = sidx < 0 ? 0.f : 1.f;
        const float4* pv = vb + (k*SS + sidx0)*32;
        float4 vA = pv[0], vB = pv[1];
        aA.x += msk*vA.x; aA.y += msk*vA.y; aA.z += msk*vA.z; aA.w += msk*vA.w;
        aB.x += msk*vB.x; aB.y += msk*vB.y; aB.z += msk*vB.z; aB.w += msk*vB.w;
      }
      float4 valA, valB;
      valA.x = pix_ok ? lrelu(aA.x) : 0.f;
      valA.y = pix_ok ? lrelu(aA.y) : 0.f;
      valA.z = pix_ok ? lrelu(aA.z) : 0.f;
      valA.w = pix_ok ? lrelu(aA.w) : 0.f;
      valB.x = pix_ok ? lrelu(aB.x) : 0.f;
      valB.y = pix_ok ? lrelu(aB.y) : 0.f;
      valB.z = pix_ok ? lrelu(aB.z) : 0.f;
      valB.w = pix_ok ? lrelu(aB.w) : 0.f;
      y1t4[pp*9 + o2*2]     = valA;
      y1t4[pp*9 + o2*2 + 1] = valB;
    }
  }
  __syncthreads();
  int pxo = tid & 63, sg = tid >> 6;
  int sgu = __builtin_amdgcn_readfirstlane(sg);
  const float* wk0 = w2t + (g*4 + sgu)*24;   // + k*384
  int ty = pxo >> 3, tx = pxo & 7;
  float p0=0.f,p1=0.f,p2=0.f;
  #pragma unroll
  for(int k=0;k<9;k++){
    int pp0 = (ty + k/3)*10 + (tx + k%3);
    float4 ya = y1t4[pp0*9 + sgu*2];
    float4 yb = y1t4[pp0*9 + sgu*2 + 1];
    const float* wk = wk0 + k*384;
    p0 += wk[0]*ya.x + wk[1]*ya.y + wk[2]*ya.z + wk[3]*ya.w
        + wk[4]*yb.x + wk[5]*yb.y + wk[6]*yb.z + wk[7]*yb.w;
    p1 += wk[8]*ya.x + wk[9]*ya.y + wk[10]*ya.z + wk[11]*ya.w
        + wk[12]*yb.x + wk[13]*yb.y + wk[14]*yb.z + wk[15]*yb.w;
    p2 += wk[16]*ya.x + wk[17]*ya.y + wk[18]*ya.z + wk[19]*ya.w
        + wk[20]*yb.x + wk[21]*yb.y + wk[22]*yb.z + wk[23]*yb.w;
  }
  part[tid]     = p0;
  part[256+tid] = p1;
  part[512+tid] = p2;
  __syncthreads();
  if(tid < 64){
    float s0 = part[tid]    +part[tid+64]    +part[tid+128]    +part[tid+192];
    float s1 = part[256+tid]+part[256+tid+64]+part[256+tid+128]+part[256+tid+192];
    float s2 = part[512+tid]+part[512+tid+64]+part[512+tid+128]+part[512+tid+192];
    int gy = y0p + (tid>>3), gx = x0p + (tid&7);
    int nidx = gy*256+gx;
    atomicAdd(&y2[(b*3+0)*NPIX+nidx], s0);
    atomicAdd(&y2[(b*3+1)*NPIX+nidx], s1);
    atomicAdd(&y2[(b*3+2)*NPIX+nidx], s2);
  }
}

// ---- per (b,channel) sum & sumsq, parallel chunks with f64 atomics ----
__global__ void k_stats(const float* __restrict__ y2, double* __restrict__ stats){
  int bc = blockIdx.x;     // 12
  int chunk = blockIdx.y;  // 8
  const float* p = y2 + (size_t)bc*NPIX + chunk*8192;
  int t = threadIdx.x;
  double s=0.0, q=0.0;
  for(int i=t;i<8192;i+=256){ double vv = (double)p[i]; s+=vv; q+=vv*vv; }
  __shared__ double rs[256], rq[256];
  rs[t]=s; rq[t]=q; __syncthreads();
  for(int st=128; st; st>>=1){ if(t<st){rs[t]+=rs[t+st]; rq[t]+=rq[t+st];} __syncthreads(); }
  if(t==0){ atomicAdd(&stats[bc*2], rs[0]); atomicAdd(&stats[bc*2+1], rq[0]); }
}

// ---- instance norm + tanh ----
__global__ void k_norm(const float* __restrict__ y2, const double* __restrict__ stats,
                       float* __restrict__ out){
  int bu = (blockIdx.x*256) >> 16;           // uniform per block
  double mu  = stats[bu*2+0] * (1.0/65536.0);
  double ex2 = stats[bu*2+1] * (1.0/65536.0);
  double var = ex2 - mu*mu;
  float inv = (float)(1.0/sqrt(var + 1e-5));
  float mf = (float)mu;
  int idx = blockIdx.x*256+threadIdx.x;
  out[idx] = tanhf((y2[idx]-mf)*inv);
}

extern "C" void kernel_launch(void* const* d_in, const int* in_sizes, int n_in,
                              void* d_out, int out_size, void* d_ws, size_t ws_size,
                              hipStream_t stream) {
  const float* z   = (const float*)d_in[0];
  const float* img = (const float*)d_in[1];
  const int*   seg = (const int*)d_in[2];
  const float* A   = (const float*)d_in[3];
  const float* pw  = (const float*)d_in[4];
  const float* pb  = (const float*)d_in[5];
  const float* bw  = (const float*)d_in[6];
  const float* bb  = (const float*)d_in[7];
  const float* a1w = (const float*)d_in[8];
  const float* a1b = (const float*)d_in[9];
  const float* a2w = (const float*)d_in[10];
  const float* a2b = (const float*)d_in[11];
  const float* w1  = (const float*)d_in[12];
  const float* b1  = (const float*)d_in[13];
  const float* w2  = (const float*)d_in[14];
  const float* b2  = (const float*)d_in[15]; (void)b2; // cancels under InstanceNorm
  float* out = (float*)d_out;

  float* ws = (float*)d_ws;
  float* segsum = ws;                    // 3072
  float* counts = ws + 3072;             // 1024 -> 4096
  float* Am     = ws + 4096;             // 1024 -> 5120
  double* stats = (double*)(ws + 5120);  // 24 doubles -> 5168, pad to 5248
  float* gb0 = ws + 5248;                // 2048
  float* gb1 = gb0 + 2048;               // 2048 -> 9344
  float* h2a = ws + 9344;                // 262144
  float* h2b = h2a + 262144;             // 262144
  float* At2 = h2b + 262144;             // 262144
  float* wT  = At2 + 262144;             // 294912
  float* v   = wT + 294912;              // 1179648
  float* y2  = v + 1179648;              // 786432
  float* w2t = y2 + 786432;              // 3456   (end ~12.2 MB)

  hipMemsetAsync(ws, 0, 5248*sizeof(float), stream);     // sums + stats
  hipMemsetAsync(y2, 0, 786432*sizeof(float), stream);   // conv2 accumulator

  float sProj = (float)sqrt(2.0/131.0);
  float s256  = (float)sqrt(2.0/256.0);
  float s512  = (float)sqrt(2.0/512.0);

  k_pp  <<<516 + 1166, 256, 0, stream>>>(img, seg, segsum, counts,
                                         A, w1, w2, At2, Am, wT, w2t);
  k_x0  <<<dim3(64,4), 256, 0, stream>>>(segsum, counts, z, pw, pb, sProj,
                                         (float4*)h2a);

  for(int blk=0; blk<NBLKS; blk++){
    const float* h2p = (blk & 1) ? h2b : h2a;
    float*       h2n = (blk & 1) ? h2a : h2b;
    const float* gbp = (blk == 0) ? (const float*)nullptr
                                  : ((blk & 1) ? gb0 : gb1);
    float*       gbn = (blk & 1) ? gb1 : gb0;
    k_iter<<<288, 512, 0, stream>>>((const float4*)h2p, gbp,
                                    (float4*)h2n, gbn,
                                    bw + blk*GCH*GCH, bb + blk*GCH,
                                    a1w + blk*512*GCH, a1b + blk*512,
                                    a2w + blk*512*512, a2b + blk*512,
                                    (const float4*)At2, Am, s256, s512);
  }
  // after 8 iters: final h2 in h2a, final gb in gb1

  k_v   <<<dim3(16,9,4), 256, 0, stream>>>((const float4*)h2a, gb1,
                                           (const float4*)wT, (float4*)v);
  k_conv<<<16384, 256, 0, stream>>>((const float4*)v, seg, (const float4*)b1, w2t, y2);
  k_stats<<<dim3(12,8), 256, 0, stream>>>(y2, stats);
  k_norm<<<3072, 256, 0, stream>>>(y2, stats, out);
}

// Round 14
// 370.772 us; speedup vs baseline: 1.8456x; 1.0832x over previous
//
#include <hip/hip_runtime.h>
#include <cmath>

#define BB 4
#define SS 256
#define ZDIM 128
#define GCH 256
#define NBLKS 8
#define NPIX 65536   // 256*256
#define U1C 128      // GC/2

__device__ __forceinline__ float lrelu(float x){ return x >= 0.f ? x : 0.2f*x; }

// ---- fused prep: pool(0..255) + A packed transpose(256..511) + wT/w2t ----
__global__ __launch_bounds__(256) void k_pp(const float* __restrict__ img,
        const int* __restrict__ seg, float* __restrict__ segsum,
        float* __restrict__ counts, const float* __restrict__ A,
        const float* __restrict__ w1, const float* __restrict__ w2,
        float* __restrict__ At2, float* __restrict__ wT, float* __restrict__ w2t){
  int bid = blockIdx.x;
  int tid = threadIdx.x;
  if(bid < 256){
    __shared__ float ls[SS*4];
    for(int j=tid;j<SS*4;j+=256) ls[j]=0.f;
    __syncthreads();
    int b = bid >> 6;
    int base = bid*1024;
    for(int it=0; it<4; it++){
      int idx = base + it*256 + tid;
      int n = idx & (NPIX-1);
      int s = seg[idx];
      atomicAdd(&ls[s*4+0], img[(b*3+0)*NPIX+n]);
      atomicAdd(&ls[s*4+1], img[(b*3+1)*NPIX+n]);
      atomicAdd(&ls[s*4+2], img[(b*3+2)*NPIX+n]);
      atomicAdd(&ls[s*4+3], 1.0f);
    }
    __syncthreads();
    for(int j=tid;j<SS*4;j+=256){
      int s = j>>2, c = j&3;
      float vv = ls[j];
      if(vv != 0.f){
        if(c<3) atomicAdd(&segsum[(b*SS+s)*3+c], vv);
        else    atomicAdd(&counts[b*SS+s], vv);
      }
    }
  } else if(bid < 512){
    __shared__ float t[32][33];
    int sb = bid - 256;
    int b = sb >> 6;
    int bx = (sb & 7)*32, by = ((sb >> 3) & 7)*32;
    int lx = tid & 31, ly4 = (tid >> 5)*4;
    #pragma unroll
    for(int r=0;r<4;r++)
      t[ly4+r][lx] = A[(b<<16) + ((by+ly4+r)<<8) + bx + lx];
    __syncthreads();
    #pragma unroll
    for(int r=0;r<4;r++){
      int jj = bx + ly4 + r;
      int i  = by + lx;
      At2[(b<<16) + ((jj>>2)<<10) + (i<<2) + (jj&3)] = t[lx][ly4+r];
    }
  } else {
    int idx = (bid-512)*256 + tid;
    if(idx < 294912){
      int o = idx & 127; int r = idx >> 7; int c = r & 255; int k = r >> 8;
      wT[idx] = w1[(o*GCH + c)*9 + k];
    } else if(idx < 294912 + 3456){
      // w2t[k*384 + g*96 + sg*48 + oc*16 + cc] = w2[oc*1152 + (g*32+sg*16+cc)*9 + k]
      int t2 = idx - 294912;
      int cc = t2 & 15;
      int oc = (t2 >> 4) % 3;
      int sg = (t2 / 48) & 1;
      int g  = (t2 / 96) & 3;
      int k  = t2 / 384;
      w2t[t2] = w2[oc*1152 + (g*32 + sg*16 + cc)*9 + k];
    }
  }
}

// ---- x0 = WSproj(concat(feats, z)) -> h2a (packed float4 over channels) ----
__global__ __launch_bounds__(256) void k_x0(const float* __restrict__ segsum,
        const float* __restrict__ counts, const float* __restrict__ z,
        const float* __restrict__ pw, const float* __restrict__ pb,
        float sc, float4* __restrict__ xp2){
  int og = blockIdx.x;              // 0..63 (channel group of 4)
  int b  = blockIdx.y;
  int i  = threadIdx.x;             // node
  float cnt = counts[b*SS+i] + 1e-6f;
  float f0 = segsum[(b*SS+i)*3+0]/cnt;
  float f1 = segsum[(b*SS+i)*3+1]/cnt;
  float f2 = segsum[(b*SS+i)*3+2]/cnt;
  const float* zb = z + b*ZDIM;
  float vals[4];
  #pragma unroll
  for(int oo=0;oo<4;oo++){
    int o = og*4 + oo;
    const float* wr = pw + o*131;
    float acc = wr[0]*f0 + wr[1]*f1 + wr[2]*f2;
    #pragma unroll 8
    for(int j=0;j<ZDIM;j++) acc += wr[3+j]*zb[j];
    vals[oo] = acc*sc + pb[o];
  }
  float4 o4 = {vals[0], vals[1], vals[2], vals[3]};
  xp2[(b*64+og)*256 + i] = o4;
}

// ---- gemm + inline AdaIN + A-propagation + node mean: 4 ch/block, K-split ----
__global__ __launch_bounds__(512) void k_gemm(const float4* __restrict__ h2prev,
        const float* __restrict__ gbPrev,
        const float* __restrict__ bw, const float* __restrict__ bb,
        const float4* __restrict__ At2, float sc,
        float4* __restrict__ h2next, float* __restrict__ m){
  int c0 = blockIdx.x*4;
  int b  = blockIdx.y;
  int tid = threadIdx.x;
  int j  = tid & 255;
  int h  = tid >> 8;               // K-half
  __shared__ float4 wl4[4][64];
  __shared__ float4 glG4[128];
  __shared__ float ps[8][260];
  __shared__ float4 h1l4[4][66];
  __shared__ float red[4][4];
  for(int t = tid; t < 1024; t += 512){
    int row = t >> 8, jj = t & 255;
    ((float*)&wl4[row][0])[jj] = bw[(c0+row)*GCH + jj];
  }
  if(gbPrev) ((float*)glG4)[tid] = gbPrev[b*512 + tid];
  __syncthreads();
  // gemm partial over K-half h, AdaIN applied inline on loads
  {
    const float4* xb = h2prev + (size_t)(b*64 + h*32)*256 + j;
    float a0=0.f, a1=0.f, a2=0.f, a3=0.f;
    if(gbPrev){
      #pragma unroll 8
      for(int kg=0; kg<32; kg++){
        float4 x = xb[kg*256];
        int kga = h*32 + kg;
        float4 g4 = glG4[kga];
        float4 t4 = glG4[64 + kga];
        x.x = lrelu(g4.x*x.x + t4.x);
        x.y = lrelu(g4.y*x.y + t4.y);
        x.z = lrelu(g4.z*x.z + t4.z);
        x.w = lrelu(g4.w*x.w + t4.w);
        float4 w0 = wl4[0][kga];
        float4 w1v= wl4[1][kga];
        float4 w2v= wl4[2][kga];
        float4 w3 = wl4[3][kga];
        a0 += w0.x*x.x + w0.y*x.y + w0.z*x.z + w0.w*x.w;
        a1 += w1v.x*x.x + w1v.y*x.y + w1v.z*x.z + w1v.w*x.w;
        a2 += w2v.x*x.x + w2v.y*x.y + w2v.z*x.z + w2v.w*x.w;
        a3 += w3.x*x.x + w3.y*x.y + w3.z*x.z + w3.w*x.w;
      }
    } else {
      #pragma unroll 8
      for(int kg=0; kg<32; kg++){
        float4 x = xb[kg*256];
        int kga = h*32 + kg;
        float4 w0 = wl4[0][kga];
        float4 w1v= wl4[1][kga];
        float4 w2v= wl4[2][kga];
        float4 w3 = wl4[3][kga];
        a0 += w0.x*x.x + w0.y*x.y + w0.z*x.z + w0.w*x.w;
        a1 += w1v.x*x.x + w1v.y*x.y + w1v.z*x.z + w1v.w*x.w;
        a2 += w2v.x*x.x + w2v.y*x.y + w2v.z*x.z + w2v.w*x.w;
        a3 += w3.x*x.x + w3.y*x.y + w3.z*x.z + w3.w*x.w;
      }
    }
    ps[0+h][j] = a0; ps[2+h][j] = a1; ps[4+h][j] = a2; ps[6+h][j] = a3;
  }
  __syncthreads();
  if(tid < 256){
    #pragma unroll
    for(int ch=0;ch<4;ch++){
      float vv = (ps[ch*2][tid] + ps[ch*2+1][tid])*sc + bb[c0+ch];
      ((float*)&h1l4[ch][0])[tid] = vv;
    }
  }
  __syncthreads();
  // propagation partial over jj-half h
  {
    const float4* ab = At2 + (size_t)(b*64 + h*32)*256 + j;
    float r0=0.f, r1=0.f, r2=0.f, r3=0.f;
    #pragma unroll 8
    for(int kg=0; kg<32; kg++){
      float4 a  = ab[kg*256];
      float4 h0 = h1l4[0][h*32+kg];
      float4 h1 = h1l4[1][h*32+kg];
      float4 h2v= h1l4[2][h*32+kg];
      float4 h3 = h1l4[3][h*32+kg];
      r0 += a.x*h0.x + a.y*h0.y + a.z*h0.z + a.w*h0.w;
      r1 += a.x*h1.x + a.y*h1.y + a.z*h1.z + a.w*h1.w;
      r2 += a.x*h2v.x + a.y*h2v.y + a.z*h2v.z + a.w*h2v.w;
      r3 += a.x*h3.x + a.y*h3.y + a.z*h3.z + a.w*h3.w;
    }
    ps[0+h][j] = r0; ps[2+h][j] = r1; ps[4+h][j] = r2; ps[6+h][j] = r3;
  }
  __syncthreads();
  float rr0=0.f, rr1=0.f, rr2=0.f, rr3=0.f;
  if(tid < 256){
    rr0 = ps[0][tid]+ps[1][tid];
    rr1 = ps[2][tid]+ps[3][tid];
    rr2 = ps[4][tid]+ps[5][tid];
    rr3 = ps[6][tid]+ps[7][tid];
    float4 o; o.x = rr0; o.y = rr1; o.z = rr2; o.w = rr3;
    h2next[(size_t)(b*64 + (c0>>2))*256 + tid] = o;
  }
  for(int off=32; off; off>>=1){
    rr0 += __shfl_down(rr0,off); rr1 += __shfl_down(rr1,off);
    rr2 += __shfl_down(rr2,off); rr3 += __shfl_down(rr3,off);
  }
  if(tid < 256 && (tid & 63)==0){
    int w3 = tid >> 6;
    red[0][w3]=rr0; red[1][w3]=rr1; red[2][w3]=rr2; red[3][w3]=rr3;
  }
  __syncthreads();
  if(tid < 4)
    m[b*GCH + c0 + tid] =
      (red[tid][0]+red[tid][1]+red[tid][2]+red[tid][3])*(1.f/256.f);
}

// ---- fused style L1 + L2: 32 blocks x 512 threads; writes gamma/beta only ----
__global__ __launch_bounds__(512) void k_s12(const float* __restrict__ m,
        const float* __restrict__ a1w, const float* __restrict__ a1b,
        const float* __restrict__ a2w, const float* __restrict__ a2b,
        float sc1, float sc2, float* __restrict__ gbNext){
  int q = blockIdx.x;               // 0..31
  int tid = threadIdx.x;
  int lane = tid & 63, wv = tid >> 6;      // wv 0..7
  int grp = lane >> 3, ll = lane & 7;
  __shared__ float4 ml4[256];       // m: [b*64 + i]
  __shared__ float s1l[4][512];     // s1 stored at [(row&7)*64 + (row>>3)]
  if(tid < 256) ml4[tid] = ((const float4*)m)[tid];
  __syncthreads();
  #pragma unroll 2
  for(int pass=0; pass<8; pass++){
    int row = wv*64 + pass*8 + grp;
    const float4* ar = (const float4*)(a1w + row*GCH) + ll;
    float p0=0.f,p1=0.f,p2=0.f,p3=0.f;
    #pragma unroll
    for(int j=0;j<8;j++){
      float4 w4 = ar[j*8];
      float4 m0 = ml4[0*64 + j*8 + ll];
      float4 m1 = ml4[1*64 + j*8 + ll];
      float4 m2 = ml4[2*64 + j*8 + ll];
      float4 m3 = ml4[3*64 + j*8 + ll];
      p0 += w4.x*m0.x + w4.y*m0.y + w4.z*m0.z + w4.w*m0.w;
      p1 += w4.x*m1.x + w4.y*m1.y + w4.z*m1.z + w4.w*m1.w;
      p2 += w4.x*m2.x + w4.y*m2.y + w4.z*m2.z + w4.w*m2.w;
      p3 += w4.x*m3.x + w4.y*m3.y + w4.z*m3.z + w4.w*m3.w;
    }
    #pragma unroll
    for(int off=1; off<8; off<<=1){
      p0 += __shfl_xor(p0,off); p1 += __shfl_xor(p1,off);
      p2 += __shfl_xor(p2,off); p3 += __shfl_xor(p3,off);
    }
    if(ll == 0){
      float bv = a1b[row];
      int sidx = ((row & 7) << 6) + (row >> 3);
      s1l[0][sidx] = lrelu(p0*sc1 + bv);
      s1l[1][sidx] = lrelu(p1*sc1 + bv);
      s1l[2][sidx] = lrelu(p2*sc1 + bv);
      s1l[3][sidx] = lrelu(p3*sc1 + bv);
    }
  }
  __syncthreads();
  float sA[4][8];
  #pragma unroll
  for(int b=0;b<4;b++)
    #pragma unroll
    for(int j=0;j<8;j++) sA[b][j] = s1l[b][j*64 + lane];
  #pragma unroll
  for(int r=0;r<2;r++){
    int ridx = wv*2 + r;            // 0..15
    int cc = ridx & 7;
    int t = (ridx < 8) ? (q*8 + cc) : (256 + q*8 + cc);
    const float* wr = a2w + t*512 + lane*8;
    float4 wa = *(const float4*)wr;
    float4 wb4 = *(const float4*)(wr+4);
    float p0 = wa.x*sA[0][0]+wa.y*sA[0][1]+wa.z*sA[0][2]+wa.w*sA[0][3]
             + wb4.x*sA[0][4]+wb4.y*sA[0][5]+wb4.z*sA[0][6]+wb4.w*sA[0][7];
    float p1 = wa.x*sA[1][0]+wa.y*sA[1][1]+wa.z*sA[1][2]+wa.w*sA[1][3]
             + wb4.x*sA[1][4]+wb4.y*sA[1][5]+wb4.z*sA[1][6]+wb4.w*sA[1][7];
    float p2 = wa.x*sA[2][0]+wa.y*sA[2][1]+wa.z*sA[2][2]+wa.w*sA[2][3]
             + wb4.x*sA[2][4]+wb4.y*sA[2][5]+wb4.z*sA[2][6]+wb4.w*sA[2][7];
    float p3 = wa.x*sA[3][0]+wa.y*sA[3][1]+wa.z*sA[3][2]+wa.w*sA[3][3]
             + wb4.x*sA[3][4]+wb4.y*sA[3][5]+wb4.z*sA[3][6]+wb4.w*sA[3][7];
    for(int off=32; off; off>>=1){
      p0 += __shfl_xor(p0,off); p1 += __shfl_xor(p1,off);
      p2 += __shfl_xor(p2,off); p3 += __shfl_xor(p3,off);
    }
    if(lane < 4){
      float p = lane==0 ? p0 : lane==1 ? p1 : lane==2 ? p2 : p3;
      gbNext[lane*512 + t] = p*sc2 + a2b[t];
    }
  }
}

// ---- v: final AdaIN applied inline during LDS staging ----
__global__ __launch_bounds__(256) void k_v(const float4* __restrict__ h2f,
        const float* __restrict__ gbF,
        const float4* __restrict__ wT4, float4* __restrict__ v4){
  int s0 = blockIdx.x*16;           // grid (16,9,4)
  int k  = blockIdx.y;
  int b  = blockIdx.z;
  int tid = threadIdx.x;
  __shared__ float4 glV4[128];
  __shared__ float4 wl[64][33];
  __shared__ float xft[256][17];
  ((float*)glV4)[tid] = gbF[b*512 + tid];
  ((float*)glV4)[256+tid] = gbF[b*512 + 256 + tid];
  __syncthreads();
  for(int t = tid; t < 1024; t += 256){
    int cg = t >> 4, si = t & 15;
    float4 xv = h2f[(size_t)(b*64 + cg)*256 + s0 + si];
    float4 g4 = glV4[cg];
    float4 t4 = glV4[64 + cg];
    xft[cg*4+0][si] = lrelu(g4.x*xv.x + t4.x);
    xft[cg*4+1][si] = lrelu(g4.y*xv.y + t4.y);
    xft[cg*4+2][si] = lrelu(g4.z*xv.z + t4.z);
    xft[cg*4+3][si] = lrelu(g4.w*xv.w + t4.w);
  }
  int og = tid & 31, sh = tid >> 5;  // sh 0..7
  const float4* wb = wT4 + (size_t)k*GCH*32;
  float4 a0 = {0.f,0.f,0.f,0.f}, a1 = {0.f,0.f,0.f,0.f};
  for(int ct=0; ct<4; ct++){
    __syncthreads();
    for(int t = tid; t < 2048; t += 256){
      int cc = t>>5, o = t&31;
      wl[cc][o] = wb[(ct*64+cc)*32 + o];
    }
    __syncthreads();
    #pragma unroll 4
    for(int cc=0;cc<64;cc++){
      float4 w = wl[cc][og];
      int c = ct*64+cc;
      float x0v = xft[c][sh];
      float x1v = xft[c][8+sh];
      a0.x += w.x*x0v; a0.y += w.y*x0v; a0.z += w.z*x0v; a0.w += w.w*x0v;
      a1.x += w.x*x1v; a1.y += w.y*x1v; a1.z += w.z*x1v; a1.w += w.w*x1v;
    }
  }
  size_t base = (size_t)(b*9+k)*SS + s0;
  v4[(base + sh)*32 + og]     = a0;
  v4[(base + 8 + sh)*32 + og] = a1;
}

// ---- fused conv1-gather(paired float4) + conv2 (scalar weights), 16x8 tile ----
__global__ __launch_bounds__(256) void k_conv(const float4* __restrict__ v4,
        const int* __restrict__ seg, const float4* __restrict__ b14,
        const float* __restrict__ w2t, float* __restrict__ y2){
  __shared__ float4 y1t4[180*9];    // [pp][8 ch-f4 + pad]  ~25.9 KB
  __shared__ int   segl[240];
  __shared__ float part[768];
  int bid = blockIdx.x;
  int x = bid & 7;
  int b = x >> 1;
  int sub = ((bid >> 3) << 1) + (x & 1);  // 0..2047
  int g = sub & 3;
  int tile = sub >> 2;                    // 0..511
  int x0p = (tile & 15)*16, y0p = (tile >> 4)*8;
  int tid = threadIdx.x;
  if(tid < 240){
    int r = tid/20, cc = tid%20;
    int gy = y0p - 2 + r, gx = x0p - 2 + cc;
    segl[tid] = (gy>=0 && gy<256 && gx>=0 && gx<256) ? seg[(b*256+gy)*256+gx] : -1;
  }
  __syncthreads();
  int o2 = tid & 3;                 // pair index: channels-f4 {o2*2, o2*2+1}
  const float4* vb = v4 + (size_t)(b*9)*SS*32 + g*8 + o2*2;
  float4 biasA = b14[g*8 + o2*2];
  float4 biasB = b14[g*8 + o2*2 + 1];
  bool interior = (x0p >= 16 && x0p <= 224 && y0p >= 8 && y0p <= 240);
  if(interior){
    for(int task = tid; task < 720; task += 256){
      int pp = task >> 2;           // 0..179, apron 18x10
      int py = pp/18, px = pp - py*18;
      float4 aA = biasA, aB = biasB;
      #pragma unroll
      for(int k=0;k<9;k++){
        int sidx = segl[(py + k/3)*20 + (px + k%3)];
        const float4* pv = vb + (k*SS + sidx)*32;
        float4 vA = pv[0], vB = pv[1];
        aA.x += vA.x; aA.y += vA.y; aA.z += vA.z; aA.w += vA.w;
        aB.x += vB.x; aB.y += vB.y; aB.z += vB.z; aB.w += vB.w;
      }
      float4 valA, valB;
      valA.x = lrelu(aA.x); valA.y = lrelu(aA.y); valA.z = lrelu(aA.z); valA.w = lrelu(aA.w);
      valB.x = lrelu(aB.x); valB.y = lrelu(aB.y); valB.z = lrelu(aB.z); valB.w = lrelu(aB.w);
      y1t4[pp*9 + o2*2]     = valA;
      y1t4[pp*9 + o2*2 + 1] = valB;
    }
  } else {
    for(int task = tid; task < 720; task += 256){
      int pp = task >> 2;
      int py = pp/18, px = pp - py*18;
      int gy = y0p - 1 + py, gx = x0p - 1 + px;
      bool pix_ok = (gy>=0 && gy<256 && gx>=0 && gx<256);
      float4 aA = biasA, aB = biasB;
      #pragma unroll
      for(int k=0;k<9;k++){
        int sidx = segl[(py + k/3)*20 + (px + k%3)];
        int sidx0 = sidx < 0 ? 0 : sidx;
        float msk = sidx < 0 ? 0.f : 1.f;
        const float4* pv = vb + (k*SS + sidx0)*32;
        float4 vA = pv[0], vB = pv[1];
        aA.x += msk*vA.x; aA.y += msk*vA.y; aA.z += msk*vA.z; aA.w += msk*vA.w;
        aB.x += msk*vB.x; aB.y += msk*vB.y; aB.z += msk*vB.z; aB.w += msk*vB.w;
      }
      float4 valA, valB;
      valA.x = pix_ok ? lrelu(aA.x) : 0.f;
      valA.y = pix_ok ? lrelu(aA.y) : 0.f;
      valA.z = pix_ok ? lrelu(aA.z) : 0.f;
      valA.w = pix_ok ? lrelu(aA.w) : 0.f;
      valB.x = pix_ok ? lrelu(aB.x) : 0.f;
      valB.y = pix_ok ? lrelu(aB.y) : 0.f;
      valB.z = pix_ok ? lrelu(aB.z) : 0.f;
      valB.w = pix_ok ? lrelu(aB.w) : 0.f;
      y1t4[pp*9 + o2*2]     = valA;
      y1t4[pp*9 + o2*2 + 1] = valB;
    }
  }
  __syncthreads();
  // conv2: 128 px x 2 channel-groups of 16
  int pxo = tid & 127, sg = tid >> 7;
  int sgu = __builtin_amdgcn_readfirstlane(sg);
  const float* wk0 = w2t + (g*2 + sgu)*48;   // + k*384
  int ty = pxo >> 4, tx = pxo & 15;
  float p0=0.f,p1=0.f,p2=0.f;
  #pragma unroll
  for(int k=0;k<9;k++){
    int pp0 = (ty + k/3)*18 + (tx + k%3);
    float4 ya = y1t4[pp0*9 + sgu*4 + 0];
    float4 yb = y1t4[pp0*9 + sgu*4 + 1];
    float4 yc = y1t4[pp0*9 + sgu*4 + 2];
    float4 yd = y1t4[pp0*9 + sgu*4 + 3];
    const float* wk = wk0 + k*384;
    p0 += wk[0]*ya.x + wk[1]*ya.y + wk[2]*ya.z + wk[3]*ya.w
        + wk[4]*yb.x + wk[5]*yb.y + wk[6]*yb.z + wk[7]*yb.w
        + wk[8]*yc.x + wk[9]*yc.y + wk[10]*yc.z + wk[11]*yc.w
        + wk[12]*yd.x + wk[13]*yd.y + wk[14]*yd.z + wk[15]*yd.w;
    p1 += wk[16]*ya.x + wk[17]*ya.y + wk[18]*ya.z + wk[19]*ya.w
        + wk[20]*yb.x + wk[21]*yb.y + wk[22]*yb.z + wk[23]*yb.w
        + wk[24]*yc.x + wk[25]*yc.y + wk[26]*yc.z + wk[27]*yc.w
        + wk[28]*yd.x + wk[29]*yd.y + wk[30]*yd.z + wk[31]*yd.w;
    p2 += wk[32]*ya.x + wk[33]*ya.y + wk[34]*ya.z + wk[35]*ya.w
        + wk[36]*yb.x + wk[37]*yb.y + wk[38]*yb.z + wk[39]*yb.w
        + wk[40]*yc.x + wk[41]*yc.y + wk[42]*yc.z + wk[43]*yc.w
        + wk[44]*yd.x + wk[45]*yd.y + wk[46]*yd.z + wk[47]*yd.w;
  }
  part[tid]     = p0;
  part[256+tid] = p1;
  part[512+tid] = p2;
  __syncthreads();
  if(tid < 128){
    float s0 = part[tid]     + part[tid+128];
    float s1 = part[256+tid] + part[256+tid+128];
    float s2 = part[512+tid] + part[512+tid+128];
    int gy = y0p + (tid>>4), gx = x0p + (tid&15);
    int nidx = gy*256+gx;
    atomicAdd(&y2[(b*3+0)*NPIX+nidx], s0);
    atomicAdd(&y2[(b*3+1)*NPIX+nidx], s1);
    atomicAdd(&y2[(b*3+2)*NPIX+nidx], s2);
  }
}

// ---- per (b,channel) sum & sumsq, parallel chunks with f64 atomics ----
__global__ void k_stats(const float* __restrict__ y2, double* __restrict__ stats){
  int bc = blockIdx.x;     // 12
  int chunk = blockIdx.y;  // 8
  const float* p = y2 + (size_t)bc*NPIX + chunk*8192;
  int t = threadIdx.x;
  double s=0.0, q=0.0;
  for(int i=t;i<8192;i+=256){ double vv = (double)p[i]; s+=vv; q+=vv*vv; }
  __shared__ double rs[256], rq[256];
  rs[t]=s; rq[t]=q; __syncthreads();
  for(int st=128; st; st>>=1){ if(t<st){rs[t]+=rs[t+st]; rq[t]+=rq[t+st];} __syncthreads(); }
  if(t==0){ atomicAdd(&stats[bc*2], rs[0]); atomicAdd(&stats[bc*2+1], rq[0]); }
}

// ---- instance norm + tanh ----
__global__ void k_norm(const float* __restrict__ y2, const double* __restrict__ stats,
                       float* __restrict__ out){
  int bu = (blockIdx.x*256) >> 16;           // uniform per block
  double mu  = stats[bu*2+0] * (1.0/65536.0);
  double ex2 = stats[bu*2+1] * (1.0/65536.0);
  double var = ex2 - mu*mu;
  float inv = (float)(1.0/sqrt(var + 1e-5));
  float mf = (float)mu;
  int idx = blockIdx.x*256+threadIdx.x;
  out[idx] = tanhf((y2[idx]-mf)*inv);
}

extern "C" void kernel_launch(void* const* d_in, const int* in_sizes, int n_in,
                              void* d_out, int out_size, void* d_ws, size_t ws_size,
                              hipStream_t stream) {
  const float* z   = (const float*)d_in[0];
  const float* img = (const float*)d_in[1];
  const int*   seg = (const int*)d_in[2];
  const float* A   = (const float*)d_in[3];
  const float* pw  = (const float*)d_in[4];
  const float* pb  = (const float*)d_in[5];
  const float* bw  = (const float*)d_in[6];
  const float* bb  = (const float*)d_in[7];
  const float* a1w = (const float*)d_in[8];
  const float* a1b = (const float*)d_in[9];
  const float* a2w = (const float*)d_in[10];
  const float* a2b = (const float*)d_in[11];
  const float* w1  = (const float*)d_in[12];
  const float* b1  = (const float*)d_in[13];
  const float* w2  = (const float*)d_in[14];
  const float* b2  = (const float*)d_in[15]; (void)b2; // cancels under InstanceNorm
  float* out = (float*)d_out;

  float* ws = (float*)d_ws;
  float* segsum = ws;                    // 3072
  float* counts = ws + 3072;             // 1024 -> 4096
  float* m      = ws + 4096;             // 1024 -> 5120
  double* stats = (double*)(ws + 5120);  // 24 doubles -> 5168, pad to 5248
  float* gb0 = ws + 5248;                // 2048
  float* gb1 = gb0 + 2048;               // 2048 -> 9344
  float* h2a = ws + 9344;                // 262144
  float* h2b = h2a + 262144;             // 262144
  float* At2 = h2b + 262144;             // 262144
  float* wT  = At2 + 262144;             // 294912
  float* v   = wT + 294912;              // 1179648
  float* y2  = v + 1179648;              // 786432
  float* w2t = y2 + 786432;              // 3456   (end ~12.2 MB)

  hipMemsetAsync(ws, 0, 5248*sizeof(float), stream);     // sums + stats
  hipMemsetAsync(y2, 0, 786432*sizeof(float), stream);   // conv2 accumulator

  float sProj = (float)sqrt(2.0/131.0);
  float s256  = (float)sqrt(2.0/256.0);
  float s512  = (float)sqrt(2.0/512.0);

  k_pp  <<<512 + 1166, 256, 0, stream>>>(img, seg, segsum, counts,
                                         A, w1, w2, At2, wT, w2t);
  k_x0  <<<dim3(64,4), 256, 0, stream>>>(segsum, counts, z, pw, pb, sProj,
                                         (float4*)h2a);

  for(int blk=0; blk<NBLKS; blk++){
    const float* h2p = (blk & 1) ? h2b : h2a;
    float*       h2n = (blk & 1) ? h2a : h2b;
    const float* gbp = (blk == 0) ? (const float*)nullptr
                                  : ((blk & 1) ? gb0 : gb1);
    float*       gbn = (blk & 1) ? gb1 : gb0;
    k_gemm<<<dim3(64,4), 512, 0, stream>>>((const float4*)h2p, gbp,
                                           bw + blk*GCH*GCH, bb + blk*GCH,
                                           (const float4*)At2, s256,
                                           (float4*)h2n, m);
    k_s12 <<<32, 512, 0, stream>>>(m, a1w + blk*512*GCH, a1b + blk*512,
                                   a2w + blk*512*512, a2b + blk*512,
                                   s256, s512, gbn);
  }
  // after 8 iters: final h2 in h2a, final gb in gb1

  k_v   <<<dim3(16,9,4), 256, 0, stream>>>((const float4*)h2a, gb1,
                                           (const float4*)wT, (float4*)v);
  k_conv<<<8192, 256, 0, stream>>>((const float4*)v, seg, (const float4*)b1, w2t, y2);
  k_stats<<<dim3(12,8), 256, 0, stream>>>(y2, stats);
  k_norm<<<3072, 256, 0, stream>>>(y2, stats, out);
}